// Round 19
// baseline (87.570 us; speedup 1.0000x reference)
//
#include <hip/hip_runtime.h>

#define NB 128
#define NS 100
#define NPRED 24
#define NHID 256
#define NSTEPS 16
#define NCTX 96
// R19 = R17 (49.8us best) with bar1/exA ELIMINATED via redundant full L1:
// every wave computes all 256 h1 channels (16 MFMA, W1F+cbias from LDS);
// the C'-layout h1 outputs chain in-register into L2's B-frags (bh identity,
// proven R2-R17). One barrier/step (double-buffered v-reduce). 800x256,
// wave w owns hidden ch [64w,64w+64) for L2 out; W2 in regs; L3 k-split.

typedef float f32x4 __attribute__((ext_vector_type(4)));
typedef short bf16x8 __attribute__((ext_vector_type(8)));

__device__ __forceinline__ unsigned short f2bf(float f) {
    union { float f; unsigned u; } v; v.f = f;
    return (unsigned short)((v.u + 0x7fffu + ((v.u >> 16) & 1u)) >> 16);
}
// 1-op RNE pack. ONLY on VALU-produced values (never raw MFMA dst) [R11].
__device__ __forceinline__ unsigned cvtpk(float lo, float hi) {
    unsigned r;
    asm("v_cvt_pk_bf16_f32 %0, %1, %2" : "=v"(r) : "v"(lo), "v"(hi));
    return r;
}
__device__ __forceinline__ bf16x8 mk8(unsigned a, unsigned b, unsigned c, unsigned d) {
    union { unsigned u[4]; bf16x8 v; } x;
    x.u[0] = a; x.u[1] = b; x.u[2] = c; x.u[3] = d;
    return x.v;
}
__device__ __forceinline__ f32x4 bf4_to_f32x4(const unsigned short* pA) {
    uint2 uu = *(const uint2*)pA;
    union { unsigned u; float f; } c0, c1, c2, c3;
    c0.u = uu.x << 16; c1.u = uu.x & 0xffff0000u;
    c2.u = uu.y << 16; c3.u = uu.y & 0xffff0000u;
    f32x4 r; r.x = c0.f; r.y = c1.f; r.z = c2.f; r.w = c3.f;
    return r;
}
__device__ __forceinline__ f32x4 relu4(f32x4 a) {
    a.x = fmaxf(a.x, 0.f); a.y = fmaxf(a.y, 0.f);
    a.z = fmaxf(a.z, 0.f); a.w = fmaxf(a.w, 0.f);
    return a;
}

// k-slot permutation within a 32-wide k-block at (lane l, elem e):
//   k_local = 16*(e>>2) + 4*(l>>4) + (e&3)
// Applied identically to A and B fragments (numerically verified R2-R18).

// prep (R17-proven): blocks 0..127 -> cbias/loc per batch row;
// blocks 128..447 -> frag images.
__global__ void prep_kernel(const float* __restrict__ past_target,
                            const float* __restrict__ W1,
                            const float* __restrict__ b1,
                            const float* __restrict__ W2,
                            const float* __restrict__ W3,
                            unsigned short* __restrict__ wsf) {
    int blk = blockIdx.x;
    if (blk < NB) {
        int b = blk, j = threadIdx.x;           // channel 0..255
        const float* ctxp = past_target + b * NCTX;
        float asum = 0.f;
        for (int k = 0; k < NCTX; k++) asum += fabsf(ctxp[k]);
        float loc = fmaxf(asum * (1.f / (float)NCTX), 1e-6f);
        float inv = 1.f / loc;
        if (j == 0) ((float*)(wsf + 114688))[b] = loc;
        float acc = b1[j];
        for (int k = 0; k < NCTX; k++)
            acc += (ctxp[k] * inv) * W1[(26 + k) * NHID + j];
        wsf[81920 + b * NHID + j] = f2bf(acc);
        return;
    }
    int i = (blk - NB) * 256 + threadIdx.x;   // 0..81919
    if (i < 8192) {
        int T = i >> 9, ll = (i >> 3) & 63, e = i & 7;
        int k = 16 * (e >> 2) + 4 * (ll >> 4) + (e & 3);
        int m = 16 * T + (ll & 15);
        wsf[i] = (k <= 24) ? f2bf(W1[k * NHID + m]) : (unsigned short)0;
    } else if (i < 16384) {
        int idx = i - 8192;
        int ks = idx >> 10, T = (idx >> 9) & 1, ll = (idx >> 3) & 63, e = idx & 7;
        int k = 32 * ks + 16 * (e >> 2) + 4 * (ll >> 4) + (e & 3);
        int m = 16 * T + (ll & 15);
        wsf[i] = (m < NPRED) ? f2bf(W3[k * NPRED + m]) : (unsigned short)0;
    } else {
        int idx = i - 16384;
        int ks = idx >> 13, T = (idx >> 9) & 15, ll = (idx >> 3) & 63, e = idx & 7;
        int k = 32 * ks + 16 * (e >> 2) + 4 * (ll >> 4) + (e & 3);
        int m = 16 * T + (ll & 15);
        wsf[i] = f2bf(W2[k * NHID + m]);
    }
}

__global__ __launch_bounds__(256, 2) void fm_kernel(
    const float* __restrict__ z0g,
    const float* __restrict__ b2, const float* __restrict__ b3,
    const unsigned short* __restrict__ wsf,
    float* __restrict__ out) {
    __shared__ __attribute__((aligned(16))) unsigned short W1L[8192]; // 16 KB
    __shared__ __attribute__((aligned(16))) unsigned short cbL[4096]; // 8 KB
    __shared__ __attribute__((aligned(16))) float vredD[2][2048];     // 16 KB

    const int tid = threadIdx.x;
    const int g = blockIdx.x;        // row-group 0..799

    // ---- stage W1F (contiguous) + cbias C-frags for this group's 16 rows ----
    {
        const uint4* src = (const uint4*)wsf;
        uint4* dst = (uint4*)W1L;
        for (int i = tid; i < 1024; i += 256) dst[i] = src[i];
        for (int idx = tid; idx < 4096; idx += 256) {
            int T = idx >> 8, r2 = idx & 255, qq = r2 >> 6, p4 = r2 & 63;
            int p = p4 >> 2, ii = p4 & 3;
            int bb = (g * 16 + p) & 127;
            cbL[idx] = wsf[81920 + bb * NHID + 16 * T + 4 * qq + ii];
        }
    }

    const int w = tid >> 6;          // wave 0..3: owns L2 out-ch [64w,64w+64)
    const int l = tid & 63;
    const int q = l >> 4, p = l & 15;
    const int R = g * 16 + p;
    const int s = R >> 7, b = R & 127;
    const int l8 = l * 8;
    const int l4 = l * 4;

    // ---- persistent registers ----
    bf16x8 w2r[32];                  // W2 A-frags (own 64 out-ch): 128 regs
    bf16x8 w3r[4];                   // W3 A-frags own ks=2w,2w+1: 16 regs
#pragma unroll
    for (int ks = 0; ks < 8; ks++)
#pragma unroll
        for (int j = 0; j < 4; j++)
            w2r[ks * 4 + j] = *(const bf16x8*)(wsf + 16384 + (ks * 16 + 4 * w + j) * 512 + l8);
#pragma unroll
    for (int d = 0; d < 2; d++)
#pragma unroll
        for (int tt = 0; tt < 2; tt++)
            w3r[2 * d + tt] = *(const bf16x8*)(wsf + 8192 + (2 * w + d) * 1024 + tt * 512 + l8);

    f32x4 b2f[4];
#pragma unroll
    for (int j = 0; j < 4; j++)
        b2f[j] = *(const f32x4*)(b2 + (4 * w + j) * 16 + 4 * q);
    f32x4 b3f0 = *(const f32x4*)(b3 + 4 * q);
    f32x4 b3f1 = {0.f, 0.f, 0.f, 0.f};
    if (q < 2) b3f1 = *(const f32x4*)(b3 + 16 + 4 * q);

    // ---- z state (replicated; all waves run identical L1 -> stays bitwise) ----
    f32x4 zs0, zs1;
    {
        const f32x4* zr = (const f32x4*)(z0g + R * NPRED);
        zs0 = zr[q];
        f32x4 zz = {0.f, 0.f, 0.f, 0.f};
        zs1 = zz;
        if (q < 2) zs1 = zr[4 + q];
    }

    __syncthreads();   // W1L + cbL ready

    const float dt = 1.f / (float)NSTEPS;
#pragma unroll 1
    for (int step = 0; step < NSTEPS; step++) {
        float* vred = &vredD[step & 1][0];
        float t = 1.f - (float)step * dt;
        float z10 = (q == 2) ? t : zs1.x;   // channel 24 carries t
        bf16x8 bz = mk8(cvtpk(zs0.x, zs0.y), cvtpk(zs0.z, zs0.w),
                        cvtpk(z10, zs1.y), cvtpk(zs1.z, zs1.w));

        // ---- layer 1 FULL (redundant per wave): 16 MFMA, h1 stays in regs ----
        // bh[2T+u] = pk(h_T elems 2u,2u+1) == exA content of R17 (identity)
        unsigned bh[32];
#pragma unroll
        for (int T = 0; T < 16; T++) {
            bf16x8 a = *(const bf16x8*)(W1L + T * 512 + l8);
            f32x4 c = bf4_to_f32x4(cbL + T * 256 + q * 64 + p * 4);
            f32x4 h = relu4(__builtin_amdgcn_mfma_f32_16x16x32_bf16(a, bz, c, 0, 0, 0));
            bh[2 * T]     = cvtpk(h.x, h.y);
            bh[2 * T + 1] = cvtpk(h.z, h.w);
        }

        // ---- layer 2 (own 64 out-ch, K=256): 32 MFMA, B from registers ----
        f32x4 a0 = {0.f, 0.f, 0.f, 0.f}, a1 = a0, a2 = a0, a3 = a0;
#pragma unroll
        for (int ks = 0; ks < 8; ks++) {
            bf16x8 bb = mk8(bh[4 * ks], bh[4 * ks + 1], bh[4 * ks + 2], bh[4 * ks + 3]);
            a0 = __builtin_amdgcn_mfma_f32_16x16x32_bf16(w2r[ks * 4 + 0], bb, a0, 0, 0, 0);
            a1 = __builtin_amdgcn_mfma_f32_16x16x32_bf16(w2r[ks * 4 + 1], bb, a1, 0, 0, 0);
            a2 = __builtin_amdgcn_mfma_f32_16x16x32_bf16(w2r[ks * 4 + 2], bb, a2, 0, 0, 0);
            a3 = __builtin_amdgcn_mfma_f32_16x16x32_bf16(w2r[ks * 4 + 3], bb, a3, 0, 0, 0);
        }
        // bias + relu + pack own h2 (VALU outputs -> cvtpk safe)
        unsigned bh2[8];
        {
            f32x4 h0 = relu4(a0 + b2f[0]), h1 = relu4(a1 + b2f[1]);
            f32x4 h2 = relu4(a2 + b2f[2]), h3 = relu4(a3 + b2f[3]);
            bh2[0] = cvtpk(h0.x, h0.y); bh2[1] = cvtpk(h0.z, h0.w);
            bh2[2] = cvtpk(h1.x, h1.y); bh2[3] = cvtpk(h1.z, h1.w);
            bh2[4] = cvtpk(h2.x, h2.y); bh2[5] = cvtpk(h2.z, h2.w);
            bh2[6] = cvtpk(h3.x, h3.y); bh2[7] = cvtpk(h3.z, h3.w);
        }

        // ---- layer 3 partial (own k-chunks ks=2w,2w+1): 4 MFMA ----
        f32x4 v0 = {0.f, 0.f, 0.f, 0.f}, v1 = v0;
        {
            bf16x8 bbA = mk8(bh2[0], bh2[1], bh2[2], bh2[3]);
            bf16x8 bbB = mk8(bh2[4], bh2[5], bh2[6], bh2[7]);
            v0 = __builtin_amdgcn_mfma_f32_16x16x32_bf16(w3r[0], bbA, v0, 0, 0, 0);
            v1 = __builtin_amdgcn_mfma_f32_16x16x32_bf16(w3r[1], bbA, v1, 0, 0, 0);
            v0 = __builtin_amdgcn_mfma_f32_16x16x32_bf16(w3r[2], bbB, v0, 0, 0, 0);
            v1 = __builtin_amdgcn_mfma_f32_16x16x32_bf16(w3r[3], bbB, v1, 0, 0, 0);
        }
        // f32 partial exchange into parity buffer (hazard-safe ds_write of
        // MFMA dst, R9/R12/R17-proven). Double-buffer makes the single
        // barrier race-free: step s+2 writes here only after bar(s+1),
        // which waves pass only with their step-s reads drained.
        *(f32x4*)(vred + (2 * w) * 256 + l4) = v0;
        *(f32x4*)(vred + (2 * w + 1) * 256 + l4) = v1;
        __syncthreads();   // the ONLY barrier per step

        // ---- all-reduce in FIXED order (z identical across waves) ----
        f32x4 sv0 = {0.f, 0.f, 0.f, 0.f}, sv1 = sv0;
#pragma unroll
        for (int w2 = 0; w2 < 4; w2++) {
            f32x4 t0 = *(const f32x4*)(vred + (2 * w2) * 256 + l4);
            f32x4 t1 = *(const f32x4*)(vred + (2 * w2 + 1) * 256 + l4);
            sv0.x += t0.x; sv0.y += t0.y; sv0.z += t0.z; sv0.w += t0.w;
            sv1.x += t1.x; sv1.y += t1.y; sv1.z += t1.z; sv1.w += t1.w;
        }

        // ---- Euler: z -= dt*(v + b3) (pad channels: v==0, b3f==0) ----
        zs0.x -= dt * (sv0.x + b3f0.x); zs0.y -= dt * (sv0.y + b3f0.y);
        zs0.z -= dt * (sv0.z + b3f0.z); zs0.w -= dt * (sv0.w + b3f0.w);
        zs1.x -= dt * (sv1.x + b3f1.x); zs1.y -= dt * (sv1.y + b3f1.y);
        zs1.z -= dt * (sv1.z + b3f1.z); zs1.w -= dt * (sv1.w + b3f1.w);
    }

    // ---- store (wave 0 only; loc from ws table) ----
    if (w == 0) {
        float loc = ((const float*)(wsf + 114688))[b];
        float* op = out + b * (NS * NPRED) + s * NPRED;
        f32x4 o0 = zs0 * loc;
        *(f32x4*)(op + 4 * q) = o0;
        if (q < 2) { f32x4 o1 = zs1 * loc; *(f32x4*)(op + 16 + 4 * q) = o1; }
    }
}

extern "C" void kernel_launch(void* const* d_in, const int* in_sizes, int n_in,
                              void* d_out, int out_size, void* d_ws, size_t ws_size,
                              hipStream_t stream) {
    const float* past_target = (const float*)d_in[0];
    // d_in[1] past_observed_values: not used by the reference math
    const float* z0 = (const float*)d_in[2];
    const float* W1 = (const float*)d_in[3];
    const float* b1 = (const float*)d_in[4];
    const float* W2 = (const float*)d_in[5];
    const float* b2 = (const float*)d_in[6];
    const float* W3 = (const float*)d_in[7];
    const float* b3 = (const float*)d_in[8];

    unsigned short* wsf = (unsigned short*)d_ws;   // ~225 KB used (R17-proven)

    prep_kernel<<<448, 256, 0, stream>>>(past_target, W1, b1, W2, W3, wsf);
    fm_kernel<<<800, 256, 0, stream>>>(z0, b2, b3, wsf, (float*)d_out);
}

// Round 20
// 53.170 us; speedup vs baseline: 1.6470x; 1.6470x over previous
//
#include <hip/hip_runtime.h>

#define NB 128
#define NS 100
#define NPRED 24
#define NHID 256
#define NSTEPS 16
#define NCTX 96
// R20 = R17 (49.8us best) + split accumulator chains:
// L2: 4 chains x 8-deep -> 8 chains x 4-deep + 1 VALU add each (halves the
// exposed MFMA-accumulate dependency latency per step).
// L3: 2 chains x 2-deep -> 4 independent MFMAs + adds.
// Everything else byte-identical to R17 (800x256, 4 waves x 64ch, W2 in
// regs, precomputed cbias/loc in prep, vectorized exchange, 2 barriers).

typedef float f32x4 __attribute__((ext_vector_type(4)));
typedef short bf16x8 __attribute__((ext_vector_type(8)));

__device__ __forceinline__ unsigned short f2bf(float f) {
    union { float f; unsigned u; } v; v.f = f;
    return (unsigned short)((v.u + 0x7fffu + ((v.u >> 16) & 1u)) >> 16);
}
// 1-op RNE pack. ONLY on VALU-produced values (never raw MFMA dst) [R11].
__device__ __forceinline__ unsigned cvtpk(float lo, float hi) {
    unsigned r;
    asm("v_cvt_pk_bf16_f32 %0, %1, %2" : "=v"(r) : "v"(lo), "v"(hi));
    return r;
}
__device__ __forceinline__ bf16x8 mk8(unsigned a, unsigned b, unsigned c, unsigned d) {
    union { unsigned u[4]; bf16x8 v; } x;
    x.u[0] = a; x.u[1] = b; x.u[2] = c; x.u[3] = d;
    return x.v;
}
__device__ __forceinline__ f32x4 bf4_to_f32x4(const unsigned short* pA) {
    uint2 uu = *(const uint2*)pA;
    union { unsigned u; float f; } c0, c1, c2, c3;
    c0.u = uu.x << 16; c1.u = uu.x & 0xffff0000u;
    c2.u = uu.y << 16; c3.u = uu.y & 0xffff0000u;
    f32x4 r; r.x = c0.f; r.y = c1.f; r.z = c2.f; r.w = c3.f;
    return r;
}
__device__ __forceinline__ f32x4 relu4(f32x4 a) {
    a.x = fmaxf(a.x, 0.f); a.y = fmaxf(a.y, 0.f);
    a.z = fmaxf(a.z, 0.f); a.w = fmaxf(a.w, 0.f);
    return a;
}

// k-slot permutation within a 32-wide k-block at (lane l, elem e):
//   k_local = 16*(e>>2) + 4*(l>>4) + (e&3)
// Applied identically to A and B fragments (numerically verified R2-R19).

// prep (R17-proven): blocks 0..127 -> cbias/loc per batch row;
// blocks 128..447 -> frag images.
__global__ void prep_kernel(const float* __restrict__ past_target,
                            const float* __restrict__ W1,
                            const float* __restrict__ b1,
                            const float* __restrict__ W2,
                            const float* __restrict__ W3,
                            unsigned short* __restrict__ wsf) {
    int blk = blockIdx.x;
    if (blk < NB) {
        int b = blk, j = threadIdx.x;           // channel 0..255
        const float* ctxp = past_target + b * NCTX;
        float asum = 0.f;
        for (int k = 0; k < NCTX; k++) asum += fabsf(ctxp[k]);
        float loc = fmaxf(asum * (1.f / (float)NCTX), 1e-6f);
        float inv = 1.f / loc;
        if (j == 0) ((float*)(wsf + 114688))[b] = loc;
        float acc = b1[j];
        for (int k = 0; k < NCTX; k++)
            acc += (ctxp[k] * inv) * W1[(26 + k) * NHID + j];
        wsf[81920 + b * NHID + j] = f2bf(acc);
        return;
    }
    int i = (blk - NB) * 256 + threadIdx.x;   // 0..81919
    if (i < 8192) {
        int T = i >> 9, ll = (i >> 3) & 63, e = i & 7;
        int k = 16 * (e >> 2) + 4 * (ll >> 4) + (e & 3);
        int m = 16 * T + (ll & 15);
        wsf[i] = (k <= 24) ? f2bf(W1[k * NHID + m]) : (unsigned short)0;
    } else if (i < 16384) {
        int idx = i - 8192;
        int ks = idx >> 10, T = (idx >> 9) & 1, ll = (idx >> 3) & 63, e = idx & 7;
        int k = 32 * ks + 16 * (e >> 2) + 4 * (ll >> 4) + (e & 3);
        int m = 16 * T + (ll & 15);
        wsf[i] = (m < NPRED) ? f2bf(W3[k * NPRED + m]) : (unsigned short)0;
    } else {
        int idx = i - 16384;
        int ks = idx >> 13, T = (idx >> 9) & 15, ll = (idx >> 3) & 63, e = idx & 7;
        int k = 32 * ks + 16 * (e >> 2) + 4 * (ll >> 4) + (e & 3);
        int m = 16 * T + (ll & 15);
        wsf[i] = f2bf(W2[k * NHID + m]);
    }
}

__global__ __launch_bounds__(256, 2) void fm_kernel(
    const float* __restrict__ z0g,
    const float* __restrict__ b2, const float* __restrict__ b3,
    const unsigned short* __restrict__ wsf,
    float* __restrict__ out) {
    // exA: h1 words, vectorized: word o at exA[(o>>2)*256 + l*4 + (o&3)]
    __shared__ __attribute__((aligned(16))) unsigned exA[2048];       // 8 KB
    // vredV: f32 partials, group (2w+i) at vredV[(2w+i)*256 + l*4 + 0..3]
    __shared__ __attribute__((aligned(16))) float vredV[2048];        // 8 KB

    const int tid = threadIdx.x;
    const int g = blockIdx.x;        // row-group 0..799

    const int w = tid >> 6;          // wave 0..3: owns hidden ch [64w,64w+64)
    const int l = tid & 63;
    const int q = l >> 4, p = l & 15;
    const int R = g * 16 + p;
    const int s = R >> 7, b = R & 127;
    const int l8 = l * 8;
    const int l4 = l * 4;

    // ---- persistent registers ----
    bf16x8 w1r[4];                   // W1 A-frags: 16 regs
    bf16x8 w2r[32];                  // W2 A-frags: 128 regs
    bf16x8 w3r[4];                   // W3 A-frags own ks=2w,2w+1: 16 regs
#pragma unroll
    for (int j = 0; j < 4; j++)
        w1r[j] = *(const bf16x8*)(wsf + (4 * w + j) * 512 + l8);
#pragma unroll
    for (int ks = 0; ks < 8; ks++)
#pragma unroll
        for (int j = 0; j < 4; j++)
            w2r[ks * 4 + j] = *(const bf16x8*)(wsf + 16384 + (ks * 16 + 4 * w + j) * 512 + l8);
#pragma unroll
    for (int d = 0; d < 2; d++)
#pragma unroll
        for (int tt = 0; tt < 2; tt++)
            w3r[2 * d + tt] = *(const bf16x8*)(wsf + 8192 + (2 * w + d) * 1024 + tt * 512 + l8);

    // cbias C-frag slice: 4 direct uint2 reads (bf16 pairs) from ws table
    f32x4 cbr[4];
#pragma unroll
    for (int j = 0; j < 4; j++)
        cbr[j] = bf4_to_f32x4(wsf + 81920 + b * NHID + (4 * w + j) * 16 + 4 * q);

    f32x4 b2f[4];
#pragma unroll
    for (int j = 0; j < 4; j++)
        b2f[j] = *(const f32x4*)(b2 + (4 * w + j) * 16 + 4 * q);
    f32x4 b3f0 = *(const f32x4*)(b3 + 4 * q);
    f32x4 b3f1 = {0.f, 0.f, 0.f, 0.f};
    if (q < 2) b3f1 = *(const f32x4*)(b3 + 16 + 4 * q);

    // ---- z state (replicated across the 4 waves; fixed-order math) ----
    f32x4 zs0, zs1;
    {
        const f32x4* zr = (const f32x4*)(z0g + R * NPRED);
        zs0 = zr[q];
        f32x4 zz = {0.f, 0.f, 0.f, 0.f};
        zs1 = zz;
        if (q < 2) zs1 = zr[4 + q];
    }

    const float dt = 1.f / (float)NSTEPS;
#pragma unroll 1
    for (int step = 0; step < NSTEPS; step++) {
        float t = 1.f - (float)step * dt;
        float z10 = (q == 2) ? t : zs1.x;   // channel 24 carries t
        // zs/z10 are VALU-produced -> cvtpk safe
        bf16x8 bz = mk8(cvtpk(zs0.x, zs0.y), cvtpk(zs0.z, zs0.w),
                        cvtpk(z10, zs1.y), cvtpk(zs1.z, zs1.w));

        // ---- layer 1 (own 64 ch): 4 MFMA -> exA, two b128 writes ----
        {
            f32x4 h0 = relu4(__builtin_amdgcn_mfma_f32_16x16x32_bf16(w1r[0], bz, cbr[0], 0, 0, 0));
            f32x4 h1 = relu4(__builtin_amdgcn_mfma_f32_16x16x32_bf16(w1r[1], bz, cbr[1], 0, 0, 0));
            uint4 t0;
            t0.x = cvtpk(h0.x, h0.y); t0.y = cvtpk(h0.z, h0.w);
            t0.z = cvtpk(h1.x, h1.y); t0.w = cvtpk(h1.z, h1.w);
            *(uint4*)(exA + (2 * w) * 256 + l4) = t0;
            f32x4 h2 = relu4(__builtin_amdgcn_mfma_f32_16x16x32_bf16(w1r[2], bz, cbr[2], 0, 0, 0));
            f32x4 h3 = relu4(__builtin_amdgcn_mfma_f32_16x16x32_bf16(w1r[3], bz, cbr[3], 0, 0, 0));
            uint4 t1;
            t1.x = cvtpk(h2.x, h2.y); t1.y = cvtpk(h2.z, h2.w);
            t1.z = cvtpk(h3.x, h3.y); t1.w = cvtpk(h3.z, h3.w);
            *(uint4*)(exA + (2 * w + 1) * 256 + l4) = t1;
        }
        __syncthreads();   // bar1: h1 exchange complete

        // ---- layer 2 (own 64 ch, K=256): 8 b128 reads + 32 MFMA ----
        // SPLIT chains: lo = ks 0..3, hi = ks 4..7 -> 4-deep each, then add.
        f32x4 zzv = {0.f, 0.f, 0.f, 0.f};
        f32x4 a0lo = zzv, a1lo = zzv, a2lo = zzv, a3lo = zzv;
        f32x4 a0hi = zzv, a1hi = zzv, a2hi = zzv, a3hi = zzv;
#pragma unroll
        for (int ks = 0; ks < 4; ks++) {
            uint4 bw = *(const uint4*)(exA + ks * 256 + l4);
            bf16x8 bb = mk8(bw.x, bw.y, bw.z, bw.w);
            a0lo = __builtin_amdgcn_mfma_f32_16x16x32_bf16(w2r[ks * 4 + 0], bb, a0lo, 0, 0, 0);
            a1lo = __builtin_amdgcn_mfma_f32_16x16x32_bf16(w2r[ks * 4 + 1], bb, a1lo, 0, 0, 0);
            a2lo = __builtin_amdgcn_mfma_f32_16x16x32_bf16(w2r[ks * 4 + 2], bb, a2lo, 0, 0, 0);
            a3lo = __builtin_amdgcn_mfma_f32_16x16x32_bf16(w2r[ks * 4 + 3], bb, a3lo, 0, 0, 0);
        }
#pragma unroll
        for (int ks = 4; ks < 8; ks++) {
            uint4 bw = *(const uint4*)(exA + ks * 256 + l4);
            bf16x8 bb = mk8(bw.x, bw.y, bw.z, bw.w);
            a0hi = __builtin_amdgcn_mfma_f32_16x16x32_bf16(w2r[ks * 4 + 0], bb, a0hi, 0, 0, 0);
            a1hi = __builtin_amdgcn_mfma_f32_16x16x32_bf16(w2r[ks * 4 + 1], bb, a1hi, 0, 0, 0);
            a2hi = __builtin_amdgcn_mfma_f32_16x16x32_bf16(w2r[ks * 4 + 2], bb, a2hi, 0, 0, 0);
            a3hi = __builtin_amdgcn_mfma_f32_16x16x32_bf16(w2r[ks * 4 + 3], bb, a3hi, 0, 0, 0);
        }
        // bias + combine halves + relu + pack own h2 (VALU -> cvtpk safe)
        unsigned bh2[8];
        {
            f32x4 h0 = relu4((a0lo + a0hi) + b2f[0]);
            f32x4 h1 = relu4((a1lo + a1hi) + b2f[1]);
            f32x4 h2 = relu4((a2lo + a2hi) + b2f[2]);
            f32x4 h3 = relu4((a3lo + a3hi) + b2f[3]);
            bh2[0] = cvtpk(h0.x, h0.y); bh2[1] = cvtpk(h0.z, h0.w);
            bh2[2] = cvtpk(h1.x, h1.y); bh2[3] = cvtpk(h1.z, h1.w);
            bh2[4] = cvtpk(h2.x, h2.y); bh2[5] = cvtpk(h2.z, h2.w);
            bh2[6] = cvtpk(h3.x, h3.y); bh2[7] = cvtpk(h3.z, h3.w);
        }

        // ---- layer 3 partial: 4 INDEPENDENT MFMAs, combine in VALU ----
        f32x4 v0, v1;
        {
            bf16x8 bbA = mk8(bh2[0], bh2[1], bh2[2], bh2[3]);
            bf16x8 bbB = mk8(bh2[4], bh2[5], bh2[6], bh2[7]);
            f32x4 v0a = __builtin_amdgcn_mfma_f32_16x16x32_bf16(w3r[0], bbA, zzv, 0, 0, 0);
            f32x4 v1a = __builtin_amdgcn_mfma_f32_16x16x32_bf16(w3r[1], bbA, zzv, 0, 0, 0);
            f32x4 v0b = __builtin_amdgcn_mfma_f32_16x16x32_bf16(w3r[2], bbB, zzv, 0, 0, 0);
            f32x4 v1b = __builtin_amdgcn_mfma_f32_16x16x32_bf16(w3r[3], bbB, zzv, 0, 0, 0);
            v0 = v0a + v0b;   // compiler VALU add of MFMA dsts: hazard-safe
            v1 = v1a + v1b;
        }
        // f32 partial exchange: two b128 writes (hazard-safe, proven path)
        *(f32x4*)(vredV + (2 * w) * 256 + l4) = v0;
        *(f32x4*)(vredV + (2 * w + 1) * 256 + l4) = v1;
        __syncthreads();   // bar2: partials ready

        // ---- all-reduce in FIXED order (z identical across waves) ----
        f32x4 sv0 = {0.f, 0.f, 0.f, 0.f}, sv1 = sv0;
#pragma unroll
        for (int w2 = 0; w2 < 4; w2++) {
            f32x4 t0 = *(const f32x4*)(vredV + (2 * w2) * 256 + l4);
            f32x4 t1 = *(const f32x4*)(vredV + (2 * w2 + 1) * 256 + l4);
            sv0.x += t0.x; sv0.y += t0.y; sv0.z += t0.z; sv0.w += t0.w;
            sv1.x += t1.x; sv1.y += t1.y; sv1.z += t1.z; sv1.w += t1.w;
        }

        // ---- Euler: z -= dt*(v + b3) (pad channels: v==0, b3f==0) ----
        zs0.x -= dt * (sv0.x + b3f0.x); zs0.y -= dt * (sv0.y + b3f0.y);
        zs0.z -= dt * (sv0.z + b3f0.z); zs0.w -= dt * (sv0.w + b3f0.w);
        zs1.x -= dt * (sv1.x + b3f1.x); zs1.y -= dt * (sv1.y + b3f1.y);
        zs1.z -= dt * (sv1.z + b3f1.z); zs1.w -= dt * (sv1.w + b3f1.w);
        // no bar here: next step's exA writes are safe (readers done pre-bar2),
        // next vredV writes are fenced by bar1 of the next step.
    }

    // ---- store (wave 0 only; loc from ws table) ----
    if (w == 0) {
        float loc = ((const float*)(wsf + 114688))[b];
        float* op = out + b * (NS * NPRED) + s * NPRED;
        f32x4 o0 = zs0 * loc;
        *(f32x4*)(op + 4 * q) = o0;
        if (q < 2) { f32x4 o1 = zs1 * loc; *(f32x4*)(op + 16 + 4 * q) = o1; }
    }
}

extern "C" void kernel_launch(void* const* d_in, const int* in_sizes, int n_in,
                              void* d_out, int out_size, void* d_ws, size_t ws_size,
                              hipStream_t stream) {
    const float* past_target = (const float*)d_in[0];
    // d_in[1] past_observed_values: not used by the reference math
    const float* z0 = (const float*)d_in[2];
    const float* W1 = (const float*)d_in[3];
    const float* b1 = (const float*)d_in[4];
    const float* W2 = (const float*)d_in[5];
    const float* b2 = (const float*)d_in[6];
    const float* W3 = (const float*)d_in[7];
    const float* b3 = (const float*)d_in[8];

    unsigned short* wsf = (unsigned short*)d_ws;   // ~225 KB used (R17-proven)

    prep_kernel<<<448, 256, 0, stream>>>(past_target, W1, b1, W2, W3, wsf);
    fm_kernel<<<800, 256, 0, stream>>>(z0, b2, b3, wsf, (float*)d_out);
}

// Round 21
// 49.653 us; speedup vs baseline: 1.7636x; 1.0708x over previous
//
#include <hip/hip_runtime.h>

#define NB 128
#define NS 100
#define NPRED 24
#define NHID 256
#define NSTEPS 16
#define NCTX 96
// FINAL (= R17, session best 49.8us): 800 blocks x 256 thr (4 waves = one
// 16-row group). Wave w owns hidden ch [64w,64w+64); W1/W2/W3 A-frag slices
// persistent in registers (W2 = 32 bf16x8 = 128 regs); cbias/loc precomputed
// per batch row in prep (kills the 100x redundant prologue that dominated
// R7-R16); vectorized b128 LDS exchange; 2 barriers/step.
// Measured landscape: every neighbor loses (W2-in-LDS 192us, 8-wave 79us,
// 1-barrier redundant-L1 88us, split-chains 53us, multi-group ILP 225us+,
// 32x32 MFMA 246us). Constraint: 2 exchanges/step x 16 steps at 2 waves/SIMD
// (register-pinned) => ~25% MfmaUtil is this algorithm's equilibrium here.

typedef float f32x4 __attribute__((ext_vector_type(4)));
typedef short bf16x8 __attribute__((ext_vector_type(8)));

__device__ __forceinline__ unsigned short f2bf(float f) {
    union { float f; unsigned u; } v; v.f = f;
    return (unsigned short)((v.u + 0x7fffu + ((v.u >> 16) & 1u)) >> 16);
}
// 1-op RNE pack. ONLY on VALU-produced values (never raw MFMA dst) [R11].
__device__ __forceinline__ unsigned cvtpk(float lo, float hi) {
    unsigned r;
    asm("v_cvt_pk_bf16_f32 %0, %1, %2" : "=v"(r) : "v"(lo), "v"(hi));
    return r;
}
__device__ __forceinline__ bf16x8 mk8(unsigned a, unsigned b, unsigned c, unsigned d) {
    union { unsigned u[4]; bf16x8 v; } x;
    x.u[0] = a; x.u[1] = b; x.u[2] = c; x.u[3] = d;
    return x.v;
}
__device__ __forceinline__ f32x4 bf4_to_f32x4(const unsigned short* pA) {
    uint2 uu = *(const uint2*)pA;
    union { unsigned u; float f; } c0, c1, c2, c3;
    c0.u = uu.x << 16; c1.u = uu.x & 0xffff0000u;
    c2.u = uu.y << 16; c3.u = uu.y & 0xffff0000u;
    f32x4 r; r.x = c0.f; r.y = c1.f; r.z = c2.f; r.w = c3.f;
    return r;
}
__device__ __forceinline__ f32x4 relu4(f32x4 a) {
    a.x = fmaxf(a.x, 0.f); a.y = fmaxf(a.y, 0.f);
    a.z = fmaxf(a.z, 0.f); a.w = fmaxf(a.w, 0.f);
    return a;
}

// k-slot permutation within a 32-wide k-block at (lane l, elem e):
//   k_local = 16*(e>>2) + 4*(l>>4) + (e&3)
// Applied identically to A and B fragments (numerically verified R2-R20).

// prep: blocks 0..127 -> cbias/loc per batch row (computed ONCE each);
// blocks 128..447 -> permuted bf16 frag images.
// ws layout (ushort idx): W1F [0,8192) | W3F [8192,16384) | W2F [16384,81920)
//   | cbias bf16 [81920,114688) | loc f32 at ushort-offset 114688.
__global__ void prep_kernel(const float* __restrict__ past_target,
                            const float* __restrict__ W1,
                            const float* __restrict__ b1,
                            const float* __restrict__ W2,
                            const float* __restrict__ W3,
                            unsigned short* __restrict__ wsf) {
    int blk = blockIdx.x;
    if (blk < NB) {
        int b = blk, j = threadIdx.x;           // channel 0..255
        const float* ctxp = past_target + b * NCTX;
        float asum = 0.f;
        for (int k = 0; k < NCTX; k++) asum += fabsf(ctxp[k]);
        float loc = fmaxf(asum * (1.f / (float)NCTX), 1e-6f);
        float inv = 1.f / loc;
        if (j == 0) ((float*)(wsf + 114688))[b] = loc;
        float acc = b1[j];
        for (int k = 0; k < NCTX; k++)
            acc += (ctxp[k] * inv) * W1[(26 + k) * NHID + j];
        wsf[81920 + b * NHID + j] = f2bf(acc);
        return;
    }
    int i = (blk - NB) * 256 + threadIdx.x;   // 0..81919
    if (i < 8192) {
        int T = i >> 9, ll = (i >> 3) & 63, e = i & 7;
        int k = 16 * (e >> 2) + 4 * (ll >> 4) + (e & 3);
        int m = 16 * T + (ll & 15);
        wsf[i] = (k <= 24) ? f2bf(W1[k * NHID + m]) : (unsigned short)0;
    } else if (i < 16384) {
        int idx = i - 8192;
        int ks = idx >> 10, T = (idx >> 9) & 1, ll = (idx >> 3) & 63, e = idx & 7;
        int k = 32 * ks + 16 * (e >> 2) + 4 * (ll >> 4) + (e & 3);
        int m = 16 * T + (ll & 15);
        wsf[i] = (m < NPRED) ? f2bf(W3[k * NPRED + m]) : (unsigned short)0;
    } else {
        int idx = i - 16384;
        int ks = idx >> 13, T = (idx >> 9) & 15, ll = (idx >> 3) & 63, e = idx & 7;
        int k = 32 * ks + 16 * (e >> 2) + 4 * (ll >> 4) + (e & 3);
        int m = 16 * T + (ll & 15);
        wsf[i] = f2bf(W2[k * NHID + m]);
    }
}

__global__ __launch_bounds__(256, 2) void fm_kernel(
    const float* __restrict__ z0g,
    const float* __restrict__ b2, const float* __restrict__ b3,
    const unsigned short* __restrict__ wsf,
    float* __restrict__ out) {
    // exA: h1 words, vectorized: word o at exA[(o>>2)*256 + l*4 + (o&3)]
    __shared__ __attribute__((aligned(16))) unsigned exA[2048];       // 8 KB
    // vredV: f32 partials, group (2w+i) at vredV[(2w+i)*256 + l*4 + 0..3]
    __shared__ __attribute__((aligned(16))) float vredV[2048];        // 8 KB

    const int tid = threadIdx.x;
    const int g = blockIdx.x;        // row-group 0..799

    const int w = tid >> 6;          // wave 0..3: owns hidden ch [64w,64w+64)
    const int l = tid & 63;
    const int q = l >> 4, p = l & 15;
    const int R = g * 16 + p;
    const int s = R >> 7, b = R & 127;
    const int l8 = l * 8;
    const int l4 = l * 4;

    // ---- persistent registers ----
    bf16x8 w1r[4];                   // W1 A-frags: 16 regs
    bf16x8 w2r[32];                  // W2 A-frags: 128 regs
    bf16x8 w3r[4];                   // W3 A-frags own ks=2w,2w+1: 16 regs
#pragma unroll
    for (int j = 0; j < 4; j++)
        w1r[j] = *(const bf16x8*)(wsf + (4 * w + j) * 512 + l8);
#pragma unroll
    for (int ks = 0; ks < 8; ks++)
#pragma unroll
        for (int j = 0; j < 4; j++)
            w2r[ks * 4 + j] = *(const bf16x8*)(wsf + 16384 + (ks * 16 + 4 * w + j) * 512 + l8);
#pragma unroll
    for (int d = 0; d < 2; d++)
#pragma unroll
        for (int tt = 0; tt < 2; tt++)
            w3r[2 * d + tt] = *(const bf16x8*)(wsf + 8192 + (2 * w + d) * 1024 + tt * 512 + l8);

    // cbias C-frag slice: 4 direct uint2 reads (bf16 pairs) from ws table
    f32x4 cbr[4];
#pragma unroll
    for (int j = 0; j < 4; j++)
        cbr[j] = bf4_to_f32x4(wsf + 81920 + b * NHID + (4 * w + j) * 16 + 4 * q);

    f32x4 b2f[4];
#pragma unroll
    for (int j = 0; j < 4; j++)
        b2f[j] = *(const f32x4*)(b2 + (4 * w + j) * 16 + 4 * q);
    f32x4 b3f0 = *(const f32x4*)(b3 + 4 * q);
    f32x4 b3f1 = {0.f, 0.f, 0.f, 0.f};
    if (q < 2) b3f1 = *(const f32x4*)(b3 + 16 + 4 * q);

    // ---- z state (replicated across the 4 waves; fixed-order math) ----
    f32x4 zs0, zs1;
    {
        const f32x4* zr = (const f32x4*)(z0g + R * NPRED);
        zs0 = zr[q];
        f32x4 zz = {0.f, 0.f, 0.f, 0.f};
        zs1 = zz;
        if (q < 2) zs1 = zr[4 + q];
    }

    const float dt = 1.f / (float)NSTEPS;
#pragma unroll 1
    for (int step = 0; step < NSTEPS; step++) {
        float t = 1.f - (float)step * dt;
        float z10 = (q == 2) ? t : zs1.x;   // channel 24 carries t
        // zs/z10 are VALU-produced -> cvtpk safe
        bf16x8 bz = mk8(cvtpk(zs0.x, zs0.y), cvtpk(zs0.z, zs0.w),
                        cvtpk(z10, zs1.y), cvtpk(zs1.z, zs1.w));

        // ---- layer 1 (own 64 ch): 4 MFMA -> exA, two b128 writes ----
        {
            f32x4 h0 = relu4(__builtin_amdgcn_mfma_f32_16x16x32_bf16(w1r[0], bz, cbr[0], 0, 0, 0));
            f32x4 h1 = relu4(__builtin_amdgcn_mfma_f32_16x16x32_bf16(w1r[1], bz, cbr[1], 0, 0, 0));
            uint4 t0;
            t0.x = cvtpk(h0.x, h0.y); t0.y = cvtpk(h0.z, h0.w);
            t0.z = cvtpk(h1.x, h1.y); t0.w = cvtpk(h1.z, h1.w);
            *(uint4*)(exA + (2 * w) * 256 + l4) = t0;
            f32x4 h2 = relu4(__builtin_amdgcn_mfma_f32_16x16x32_bf16(w1r[2], bz, cbr[2], 0, 0, 0));
            f32x4 h3 = relu4(__builtin_amdgcn_mfma_f32_16x16x32_bf16(w1r[3], bz, cbr[3], 0, 0, 0));
            uint4 t1;
            t1.x = cvtpk(h2.x, h2.y); t1.y = cvtpk(h2.z, h2.w);
            t1.z = cvtpk(h3.x, h3.y); t1.w = cvtpk(h3.z, h3.w);
            *(uint4*)(exA + (2 * w + 1) * 256 + l4) = t1;
        }
        __syncthreads();   // bar1: h1 exchange complete

        // ---- layer 2 (own 64 ch, K=256): 8 b128 reads + 32 MFMA ----
        f32x4 a0 = {0.f, 0.f, 0.f, 0.f}, a1 = a0, a2 = a0, a3 = a0;
#pragma unroll
        for (int ks = 0; ks < 8; ks++) {
            uint4 bw = *(const uint4*)(exA + ks * 256 + l4);
            bf16x8 bb = mk8(bw.x, bw.y, bw.z, bw.w);
            a0 = __builtin_amdgcn_mfma_f32_16x16x32_bf16(w2r[ks * 4 + 0], bb, a0, 0, 0, 0);
            a1 = __builtin_amdgcn_mfma_f32_16x16x32_bf16(w2r[ks * 4 + 1], bb, a1, 0, 0, 0);
            a2 = __builtin_amdgcn_mfma_f32_16x16x32_bf16(w2r[ks * 4 + 2], bb, a2, 0, 0, 0);
            a3 = __builtin_amdgcn_mfma_f32_16x16x32_bf16(w2r[ks * 4 + 3], bb, a3, 0, 0, 0);
        }
        // bias + relu + pack own h2 (VALU outputs -> cvtpk safe)
        unsigned bh2[8];
        {
            f32x4 h0 = relu4(a0 + b2f[0]), h1 = relu4(a1 + b2f[1]);
            f32x4 h2 = relu4(a2 + b2f[2]), h3 = relu4(a3 + b2f[3]);
            bh2[0] = cvtpk(h0.x, h0.y); bh2[1] = cvtpk(h0.z, h0.w);
            bh2[2] = cvtpk(h1.x, h1.y); bh2[3] = cvtpk(h1.z, h1.w);
            bh2[4] = cvtpk(h2.x, h2.y); bh2[5] = cvtpk(h2.z, h2.w);
            bh2[6] = cvtpk(h3.x, h3.y); bh2[7] = cvtpk(h3.z, h3.w);
        }

        // ---- layer 3 partial (own k-chunks ks=2w,2w+1): 4 MFMA ----
        f32x4 v0 = {0.f, 0.f, 0.f, 0.f}, v1 = v0;
        {
            bf16x8 bbA = mk8(bh2[0], bh2[1], bh2[2], bh2[3]);
            bf16x8 bbB = mk8(bh2[4], bh2[5], bh2[6], bh2[7]);
            v0 = __builtin_amdgcn_mfma_f32_16x16x32_bf16(w3r[0], bbA, v0, 0, 0, 0);
            v1 = __builtin_amdgcn_mfma_f32_16x16x32_bf16(w3r[1], bbA, v1, 0, 0, 0);
            v0 = __builtin_amdgcn_mfma_f32_16x16x32_bf16(w3r[2], bbB, v0, 0, 0, 0);
            v1 = __builtin_amdgcn_mfma_f32_16x16x32_bf16(w3r[3], bbB, v1, 0, 0, 0);
        }
        // f32 partial exchange: two b128 writes (hazard-safe, proven path)
        *(f32x4*)(vredV + (2 * w) * 256 + l4) = v0;
        *(f32x4*)(vredV + (2 * w + 1) * 256 + l4) = v1;
        __syncthreads();   // bar2: partials ready

        // ---- all-reduce in FIXED order (z identical across waves) ----
        f32x4 sv0 = {0.f, 0.f, 0.f, 0.f}, sv1 = sv0;
#pragma unroll
        for (int w2 = 0; w2 < 4; w2++) {
            f32x4 t0 = *(const f32x4*)(vredV + (2 * w2) * 256 + l4);
            f32x4 t1 = *(const f32x4*)(vredV + (2 * w2 + 1) * 256 + l4);
            sv0.x += t0.x; sv0.y += t0.y; sv0.z += t0.z; sv0.w += t0.w;
            sv1.x += t1.x; sv1.y += t1.y; sv1.z += t1.z; sv1.w += t1.w;
        }

        // ---- Euler: z -= dt*(v + b3) (pad channels: v==0, b3f==0) ----
        zs0.x -= dt * (sv0.x + b3f0.x); zs0.y -= dt * (sv0.y + b3f0.y);
        zs0.z -= dt * (sv0.z + b3f0.z); zs0.w -= dt * (sv0.w + b3f0.w);
        zs1.x -= dt * (sv1.x + b3f1.x); zs1.y -= dt * (sv1.y + b3f1.y);
        zs1.z -= dt * (sv1.z + b3f1.z); zs1.w -= dt * (sv1.w + b3f1.w);
        // no bar here: next step's exA writes are safe (readers done pre-bar2),
        // next vredV writes are fenced by bar1 of the next step.
    }

    // ---- store (wave 0 only; loc from ws table) ----
    if (w == 0) {
        float loc = ((const float*)(wsf + 114688))[b];
        float* op = out + b * (NS * NPRED) + s * NPRED;
        f32x4 o0 = zs0 * loc;
        *(f32x4*)(op + 4 * q) = o0;
        if (q < 2) { f32x4 o1 = zs1 * loc; *(f32x4*)(op + 16 + 4 * q) = o1; }
    }
}

extern "C" void kernel_launch(void* const* d_in, const int* in_sizes, int n_in,
                              void* d_out, int out_size, void* d_ws, size_t ws_size,
                              hipStream_t stream) {
    const float* past_target = (const float*)d_in[0];
    // d_in[1] past_observed_values: not used by the reference math
    const float* z0 = (const float*)d_in[2];
    const float* W1 = (const float*)d_in[3];
    const float* b1 = (const float*)d_in[4];
    const float* W2 = (const float*)d_in[5];
    const float* b2 = (const float*)d_in[6];
    const float* W3 = (const float*)d_in[7];
    const float* b3 = (const float*)d_in[8];

    unsigned short* wsf = (unsigned short*)d_ws;   // ~225 KB used (proven)

    prep_kernel<<<448, 256, 0, stream>>>(past_target, W1, b1, W2, W3, wsf);
    fm_kernel<<<800, 256, 0, stream>>>(z0, b2, b3, wsf, (float*)d_out);
}